// Round 3
// baseline (65.320 us; speedup 1.0000x reference)
//
#include <hip/hip_runtime.h>

// Problem: B=16, F=1024 (32x32 image), Ci=64, Co=64, K=4, R=1.
// out[b, h*32+w, co] = log( sum_ci exp(ll[b,f,ci]) * exp(logits[co,ci,kh,kw]) )
//                      - log( sum_ci exp(logits[co,ci,kh,kw]) ),  kh=h%4, kw=w%4.
#define CI 64
#define CO 64
#define F_ 1024
#define KK 4
#define NPAT 16

// E/LS tables live in module-scope device globals (256 KB + 4 KB), not d_ws:
// the harness re-poisons the 256 MiB workspace unconditionally (40 us fill,
// confirmed R1->R2), so d_ws is never touched.
__device__ float E_buf[NPAT * CI * CO];
__device__ float LS_buf[NPAT * CO];

// Broadcast lane `ci`'s value to all lanes via the LDS pipe (ds_bpermute,
// no LDS storage) instead of v_readlane (VALU pipe) — frees VALU issue slots
// so the 256 fmas overlap with the 256 broadcasts.
__device__ __forceinline__ float bcast(float v, int ci_byte) {
    return __int_as_float(__builtin_amdgcn_ds_bpermute(ci_byte, __float_as_int(v)));
}

// ---------------- kernel 1: prep (16 blocks) ----------------
// E[pat][g][co][k] = exp(logits[co][ci=4g+k][pat])   (float4-friendly for main)
// LS[pat][co]      = log(sum_ci exp(logits[co][ci][pat]))
__global__ __launch_bounds__(256) void prep_kernel(
    const float* __restrict__ logits)
{
    const int pat = blockIdx.x;              // 0..15
    const int t   = threadIdx.x;
    const int co  = t & 63;
    const int i   = t >> 6;                  // 0..3
    float psum = 0.f;
    #pragma unroll
    for (int g4 = 0; g4 < 4; ++g4) {
        const int g = i * 4 + g4;            // float4 group = ci/4
        float4 e;
        e.x = __expf(logits[co * (CI * KK * KK) + (4 * g + 0) * (KK * KK) + pat]);
        e.y = __expf(logits[co * (CI * KK * KK) + (4 * g + 1) * (KK * KK) + pat]);
        e.z = __expf(logits[co * (CI * KK * KK) + (4 * g + 2) * (KK * KK) + pat]);
        e.w = __expf(logits[co * (CI * KK * KK) + (4 * g + 3) * (KK * KK) + pat]);
        *reinterpret_cast<float4*>(&E_buf[pat * (CI * CO) + g * (CO * 4) + co * 4]) = e;
        psum += (e.x + e.y) + (e.z + e.w);
    }
    __shared__ float red[4][64];
    red[i][co] = psum;
    __syncthreads();
    if (t < 64)
        LS_buf[pat * 64 + t] =
            __logf((red[0][t] + red[1][t]) + (red[2][t] + red[3][t]));
}

// ---------------- kernel 2: main (1024 blocks, no barriers) ----------------
// lane = co (compute/store) = ci (ll load). Each wave: 4 positions of one pattern.
__global__ __launch_bounds__(256, 4) void main_kernel(
    const float* __restrict__ ll, float* __restrict__ out)
{
    const int tid   = threadIdx.x;
    const int lane  = tid & 63;
    const int wv    = tid >> 6;
    const int bid   = blockIdx.x;            // 1024
    const int pat   = bid & (NPAT - 1);
    const int chunk = bid >> 4;              // 0..63
    const int kh = pat >> 2, kw = pat & 3;

    // ---- issue the 4 HBM loads first (longest latency) ----
    int   idx[4];
    float p[4];
    #pragma unroll
    for (int j = 0; j < 4; ++j) {
        const int pr = (chunk << 4) + (wv << 2) + j;   // b*64 + oh*8 + ow
        const int b  = pr >> 6;
        const int oh = (pr >> 3) & 7;
        const int ow = pr & 7;
        const int f  = (oh * 4 + kh) * 32 + (ow * 4 + kw);
        idx[j] = (b * F_ + f) * CI + lane;             // coalesced 256 B / wave
        p[j]   = ll[idx[j]];
    }

    // ---- weights: 16 coalesced float4 loads (L2-hot), lane = co ----
    float4 wv4[16];
    const float4* Ep4 = reinterpret_cast<const float4*>(E_buf + pat * (CI * CO)) + lane;
    #pragma unroll
    for (int g = 0; g < 16; ++g) wv4[g] = Ep4[g * CO];

    // ---- lsum precomputed in prep (replaces a ~90-inst reduction tree) ----
    const float lsum = LS_buf[pat * 64 + lane];

    float wreg[CI];
    #pragma unroll
    for (int g = 0; g < 16; ++g) {
        wreg[4 * g + 0] = wv4[g].x; wreg[4 * g + 1] = wv4[g].y;
        wreg[4 * g + 2] = wv4[g].z; wreg[4 * g + 3] = wv4[g].w;
    }

    // ---- exp, then broadcast via ds_bpermute (LDS pipe, overlaps VALU) ----
    #pragma unroll
    for (int j = 0; j < 4; ++j) p[j] = __expf(p[j]);

    float a0[4] = {0.f,0.f,0.f,0.f}, a1[4] = {0.f,0.f,0.f,0.f};
    float a2[4] = {0.f,0.f,0.f,0.f}, a3[4] = {0.f,0.f,0.f,0.f};
    #pragma unroll
    for (int ci = 0; ci < CI; ci += 4) {
        #pragma unroll
        for (int j = 0; j < 4; ++j) {
            a0[j] = fmaf(bcast(p[j], 4 * (ci + 0)), wreg[ci + 0], a0[j]);
            a1[j] = fmaf(bcast(p[j], 4 * (ci + 1)), wreg[ci + 1], a1[j]);
            a2[j] = fmaf(bcast(p[j], 4 * (ci + 2)), wreg[ci + 2], a2[j]);
            a3[j] = fmaf(bcast(p[j], 4 * (ci + 3)), wreg[ci + 3], a3[j]);
        }
    }
    #pragma unroll
    for (int j = 0; j < 4; ++j)
        out[idx[j]] = __logf((a0[j] + a1[j]) + (a2[j] + a3[j])) - lsum;  // coalesced
}

extern "C" void kernel_launch(void* const* d_in, const int* in_sizes, int n_in,
                              void* d_out, int out_size, void* d_ws, size_t ws_size,
                              hipStream_t stream) {
    const float* ll     = (const float*)d_in[0];
    const float* logits = (const float*)d_in[1];
    float* out = (float*)d_out;
    (void)d_ws; (void)ws_size;               // workspace deliberately unused
    prep_kernel<<<dim3(16), dim3(256), 0, stream>>>(logits);
    main_kernel<<<dim3(1024), dim3(256), 0, stream>>>(ll, out);
}

// Round 4
// 65.200 us; speedup vs baseline: 1.0018x; 1.0018x over previous
//
#include <hip/hip_runtime.h>

// Problem: B=16, F=1024 (32x32 image), Ci=64, Co=64, K=4, R=1.
// out[b, h*32+w, co] = log( sum_ci exp(ll[b,f,ci]) * exp(logits[co,ci,kh,kw]) )
//                      - log( sum_ci exp(logits[co,ci,kh,kw]) ),  kh=h%4, kw=w%4.
#define CI 64
#define CO 64
#define F_ 1024
#define KK 4
#define NPAT 16

// E/LS tables in module-scope device globals (256 KB + 4 KB), not d_ws:
// the harness re-poisons the 256 MiB workspace unconditionally (40 us fill,
// confirmed R1->R2), so d_ws is never touched.
__device__ float E_buf[NPAT * CI * CO];
__device__ float LS_buf[NPAT * CO];

// v_readlane broadcast (VALU pipe). Measured best (R1/R2); the ds_bpermute
// variant (R3) exposed a ~25-cyc dependent LDS-pipe chain and regressed.
__device__ __forceinline__ float bcast(float v, int l) {
    return __int_as_float(__builtin_amdgcn_readlane(__float_as_int(v), l));
}

// ---------------- kernel 1: prep (16 blocks) ----------------
// E[pat][g][co][k] = exp(logits[co][ci=4g+k][pat])   (float4-friendly for main)
// LS[pat][co]      = log(sum_ci exp(logits[co][ci][pat]))
__global__ __launch_bounds__(256) void prep_kernel(
    const float* __restrict__ logits)
{
    const int pat = blockIdx.x;              // 0..15
    const int t   = threadIdx.x;
    const int co  = t & 63;
    const int i   = t >> 6;                  // 0..3
    float psum = 0.f;
    #pragma unroll
    for (int g4 = 0; g4 < 4; ++g4) {
        const int g = i * 4 + g4;            // float4 group = ci/4
        float4 e;
        e.x = __expf(logits[co * (CI * KK * KK) + (4 * g + 0) * (KK * KK) + pat]);
        e.y = __expf(logits[co * (CI * KK * KK) + (4 * g + 1) * (KK * KK) + pat]);
        e.z = __expf(logits[co * (CI * KK * KK) + (4 * g + 2) * (KK * KK) + pat]);
        e.w = __expf(logits[co * (CI * KK * KK) + (4 * g + 3) * (KK * KK) + pat]);
        *reinterpret_cast<float4*>(&E_buf[pat * (CI * CO) + g * (CO * 4) + co * 4]) = e;
        psum += (e.x + e.y) + (e.z + e.w);
    }
    __shared__ float red[4][64];
    red[i][co] = psum;
    __syncthreads();
    if (t < 64)
        LS_buf[pat * 64 + t] =
            __logf((red[0][t] + red[1][t]) + (red[2][t] + red[3][t]));
}

// ---------------- kernel 2: main (1024 blocks, no LDS, no barriers) ----------------
// lane = co (compute/store) = ci (ll load). Each wave: 4 positions of one pattern.
__global__ __launch_bounds__(256, 4) void main_kernel(
    const float* __restrict__ ll, float* __restrict__ out)
{
    const int tid   = threadIdx.x;
    const int lane  = tid & 63;
    const int wv    = tid >> 6;
    const int bid   = blockIdx.x;            // 1024
    const int pat   = bid & (NPAT - 1);
    const int chunk = bid >> 4;              // 0..63
    const int kh = pat >> 2, kw = pat & 3;

    // ---- issue the 4 HBM loads first (longest latency) ----
    int   idx[4];
    float p[4];
    #pragma unroll
    for (int j = 0; j < 4; ++j) {
        const int pr = (chunk << 4) + (wv << 2) + j;   // b*64 + oh*8 + ow
        const int b  = pr >> 6;
        const int oh = (pr >> 3) & 7;
        const int ow = pr & 7;
        const int f  = (oh * 4 + kh) * 32 + (ow * 4 + kw);
        idx[j] = (b * F_ + f) * CI + lane;             // coalesced 256 B / wave
        p[j]   = ll[idx[j]];
    }

    // ---- weights: 16 coalesced float4 loads (L2-hot), lane = co ----
    float4 wv4[16];
    const float4* Ep4 = reinterpret_cast<const float4*>(E_buf + pat * (CI * CO)) + lane;
    #pragma unroll
    for (int g = 0; g < 16; ++g) wv4[g] = Ep4[g * CO];

    // ---- lsum precomputed in prep (removes ~90-inst reduction tree) ----
    const float lsum = LS_buf[pat * 64 + lane];

    float wreg[CI];
    #pragma unroll
    for (int g = 0; g < 16; ++g) {
        wreg[4 * g + 0] = wv4[g].x; wreg[4 * g + 1] = wv4[g].y;
        wreg[4 * g + 2] = wv4[g].z; wreg[4 * g + 3] = wv4[g].w;
    }

    // ---- exp, then broadcast via v_readlane (VALU pipe, no LDS) ----
    #pragma unroll
    for (int j = 0; j < 4; ++j) p[j] = __expf(p[j]);

    float a0[4] = {0.f,0.f,0.f,0.f}, a1[4] = {0.f,0.f,0.f,0.f};
    float a2[4] = {0.f,0.f,0.f,0.f}, a3[4] = {0.f,0.f,0.f,0.f};
    #pragma unroll
    for (int ci = 0; ci < CI; ci += 4) {
        #pragma unroll
        for (int j = 0; j < 4; ++j) {
            a0[j] = fmaf(bcast(p[j], ci + 0), wreg[ci + 0], a0[j]);
            a1[j] = fmaf(bcast(p[j], ci + 1), wreg[ci + 1], a1[j]);
            a2[j] = fmaf(bcast(p[j], ci + 2), wreg[ci + 2], a2[j]);
            a3[j] = fmaf(bcast(p[j], ci + 3), wreg[ci + 3], a3[j]);
        }
    }
    #pragma unroll
    for (int j = 0; j < 4; ++j)
        out[idx[j]] = __logf((a0[j] + a1[j]) + (a2[j] + a3[j])) - lsum;  // coalesced
}

extern "C" void kernel_launch(void* const* d_in, const int* in_sizes, int n_in,
                              void* d_out, int out_size, void* d_ws, size_t ws_size,
                              hipStream_t stream) {
    const float* ll     = (const float*)d_in[0];
    const float* logits = (const float*)d_in[1];
    float* out = (float*)d_out;
    (void)d_ws; (void)ws_size;               // workspace deliberately unused
    prep_kernel<<<dim3(16), dim3(256), 0, stream>>>(logits);
    main_kernel<<<dim3(1024), dim3(256), 0, stream>>>(ll, out);
}